// Round 1
// baseline (88.415 us; speedup 1.0000x reference)
//
#include <hip/hip_runtime.h>

// L1 attention: out[b,i,j,h] = -scale * sum_d |q[b,i,h,d] - k[b,j,h,d]|
// B=2, T=512, H=8, D=64, scale = 1/sqrt(64) = 0.125
// out shape (B, T, T, H), h innermost.

#define TDIM 512
#define HDIM 8
#define DDIM 64
#define TILE 64
#define PAD  76   // LDS row stride in floats: bank step 12 -> 2-way max on b128 reads

__global__ __launch_bounds__(256) void l1attn_kernel(
    const float* __restrict__ q, const float* __restrict__ k,
    float* __restrict__ out)
{
    __shared__ float qs[TILE * PAD];
    __shared__ float ks[TILE * PAD];

    const int t   = threadIdx.x;
    const int jt  = blockIdx.x * TILE;
    const int it  = blockIdx.y * TILE;
    const int bh  = blockIdx.z;          // b*8 + h
    const int b   = bh >> 3;
    const int h   = bh & 7;

    const float* qb = q + (((size_t)(b * TDIM + it)) * HDIM + h) * DDIM;
    const float* kb = k + (((size_t)(b * TDIM + jt)) * HDIM + h) * DDIM;

    const int lane16 = t & 15;    // covers 64 floats of a row as 16 x float4
    const int grp    = t >> 4;    // 0..15

    // Stage 64 rows of q and k for this (b,h) into LDS (row stride H*D = 512 floats in global)
    #pragma unroll
    for (int c = 0; c < 4; ++c) {
        int row = c * 16 + grp;
        float4 vq = *(const float4*)(qb + (size_t)row * (HDIM * DDIM) + lane16 * 4);
        float4 vk = *(const float4*)(kb + (size_t)row * (HDIM * DDIM) + lane16 * 4);
        *(float4*)&qs[row * PAD + lane16 * 4] = vq;
        *(float4*)&ks[row * PAD + lane16 * 4] = vk;
    }
    __syncthreads();

    const int ty = grp;     // i micro-tile index
    const int tx = lane16;  // j micro-tile index

    float acc[4][4];
    #pragma unroll
    for (int r = 0; r < 4; ++r)
        #pragma unroll
        for (int s = 0; s < 4; ++s) acc[r][s] = 0.f;

    #pragma unroll 4
    for (int d = 0; d < DDIM; d += 4) {
        float4 qv[4], kv[4];
        #pragma unroll
        for (int r = 0; r < 4; ++r) qv[r] = *(float4*)&qs[(ty * 4 + r) * PAD + d];
        #pragma unroll
        for (int s = 0; s < 4; ++s) kv[s] = *(float4*)&ks[(tx * 4 + s) * PAD + d];
        #pragma unroll
        for (int r = 0; r < 4; ++r)
            #pragma unroll
            for (int s = 0; s < 4; ++s) {
                acc[r][s] += fabsf(qv[r].x - kv[s].x);
                acc[r][s] += fabsf(qv[r].y - kv[s].y);
                acc[r][s] += fabsf(qv[r].z - kv[s].z);
                acc[r][s] += fabsf(qv[r].w - kv[s].w);
            }
    }

    // out[b][i][j][h], h innermost
    #pragma unroll
    for (int r = 0; r < 4; ++r) {
        size_t i = it + ty * 4 + r;
        size_t base = ((size_t)(b * TDIM) + i) * TDIM;
        #pragma unroll
        for (int s = 0; s < 4; ++s) {
            size_t j = jt + tx * 4 + s;
            out[(base + j) * HDIM + h] = acc[r][s] * -0.125f;
        }
    }
}

extern "C" void kernel_launch(void* const* d_in, const int* in_sizes, int n_in,
                              void* d_out, int out_size, void* d_ws, size_t ws_size,
                              hipStream_t stream) {
    const float* q = (const float*)d_in[0];
    const float* k = (const float*)d_in[1];
    float* out = (float*)d_out;
    const int B = in_sizes[0] / (TDIM * HDIM * DDIM);   // = 2
    dim3 grid(TDIM / TILE, TDIM / TILE, B * HDIM);      // (8, 8, 16)
    l1attn_kernel<<<grid, 256, 0, stream>>>(q, k, out);
}

// Round 2
// 84.760 us; speedup vs baseline: 1.0431x; 1.0431x over previous
//
#include <hip/hip_runtime.h>

// L1 attention: out[b,i,j,h] = -0.125 * sum_d |q[b,i,h,d] - k[b,j,h,d]|
// B=2, T=512, H=8, D=64.  out shape (B, T, T, H), h innermost.
//
// Block: 256 threads = 4 waves, covers a 32x32 (i,j) tile for ALL 8 h
// (two staging passes of 4 h each; wave w computes h = 4*p + w).
// LDS row stride 260 floats: 260/4 = 65 ≡ 1 (mod 8) 16B-bank-groups, so
// b128 reads across the 8 tx (or ty) lanes cover all 8 bank-group windows
// -> conflict-free.  All 8 h of every 64B output line are produced by
// waves of the same block (same CU) -> L2 assembles full lines.

#define TDIM 512
#define HDIM 8
#define DDIM 64
#define ITILE 32
#define JTILE 32
#define ROWF 256      // 4 h * 64 d floats staged per row per pass
#define PADS 260      // LDS row stride in floats

__global__ __launch_bounds__(256, 2) void l1attn_kernel(
    const float* __restrict__ q, const float* __restrict__ k,
    float* __restrict__ out)
{
    __shared__ float qs[ITILE * PADS];
    __shared__ float ks[JTILE * PADS];

    const int t    = threadIdx.x;
    const int jt   = blockIdx.x * JTILE;
    const int it   = blockIdx.y * ITILE;
    const int b    = blockIdx.z;

    const int w    = t >> 6;       // wave id 0..3 -> h within the pass
    const int lane = t & 63;
    const int tx   = lane & 7;     // j micro base
    const int ty   = lane >> 3;    // i micro base

    #pragma unroll
    for (int p = 0; p < 2; ++p) {
        // ---- stage 32 q-rows and 32 k-rows, h in [4p, 4p+4), into LDS ----
        // chunk = c*256 + t over 2048 float4-chunks: row = chunk/64, col4 = chunk%64
        #pragma unroll
        for (int c = 0; c < 8; ++c) {
            int chunk = c * 256 + t;
            int row   = chunk >> 6;
            int col4  = chunk & 63;
            // q[b][it+row][h][d] flat = (b*512 + it+row)*512 + p*256 + col4*4
            float4 vq = *(const float4*)(q + ((size_t)(b * TDIM + it + row)) * (HDIM * DDIM)
                                           + p * ROWF + col4 * 4);
            float4 vk = *(const float4*)(k + ((size_t)(b * TDIM + jt + row)) * (HDIM * DDIM)
                                           + p * ROWF + col4 * 4);
            *(float4*)&qs[row * PADS + col4 * 4] = vq;
            *(float4*)&ks[row * PADS + col4 * 4] = vk;
        }
        __syncthreads();

        // ---- compute: wave w handles h = 4p + w ----
        const float* qbase = &qs[w * DDIM];   // h-offset within staged row
        const float* kbase = &ks[w * DDIM];

        float acc[4][4];
        #pragma unroll
        for (int r = 0; r < 4; ++r)
            #pragma unroll
            for (int s = 0; s < 4; ++s) acc[r][s] = 0.f;

        #pragma unroll 4
        for (int d = 0; d < DDIM; d += 4) {
            float4 qv[4], kv[4];
            #pragma unroll
            for (int r = 0; r < 4; ++r)
                qv[r] = *(const float4*)&qbase[(ty + 8 * r) * PADS + d];
            #pragma unroll
            for (int s = 0; s < 4; ++s)
                kv[s] = *(const float4*)&kbase[(tx + 8 * s) * PADS + d];
            #pragma unroll
            for (int r = 0; r < 4; ++r)
                #pragma unroll
                for (int s = 0; s < 4; ++s) {
                    acc[r][s] += fabsf(qv[r].x - kv[s].x);
                    acc[r][s] += fabsf(qv[r].y - kv[s].y);
                    acc[r][s] += fabsf(qv[r].z - kv[s].z);
                    acc[r][s] += fabsf(qv[r].w - kv[s].w);
                }
        }

        // ---- write: out[b][i][j][h], h = 4p + w ----
        const int h = p * 4 + w;
        #pragma unroll
        for (int r = 0; r < 4; ++r) {
            size_t i    = (size_t)(it + ty + 8 * r);
            size_t base = ((size_t)(b * TDIM) + i) * TDIM;
            #pragma unroll
            for (int s = 0; s < 4; ++s) {
                size_t j = (size_t)(jt + tx + 8 * s);
                out[(base + j) * HDIM + h] = acc[r][s] * -0.125f;
            }
        }
        __syncthreads();   // before next pass overwrites LDS
    }
}

extern "C" void kernel_launch(void* const* d_in, const int* in_sizes, int n_in,
                              void* d_out, int out_size, void* d_ws, size_t ws_size,
                              hipStream_t stream) {
    const float* q = (const float*)d_in[0];
    const float* k = (const float*)d_in[1];
    float* out = (float*)d_out;
    const int B = in_sizes[0] / (TDIM * HDIM * DDIM);   // = 2
    dim3 grid(TDIM / JTILE, TDIM / ITILE, B);            // (16, 16, 2)
    l1attn_kernel<<<grid, 256, 0, stream>>>(q, k, out);
}